// Round 3
// baseline (72.125 us; speedup 1.0000x reference)
//
#include <hip/hip_runtime.h>

// Problem constants (match reference): B=8, D=H=W=128, C=2, fp32.
constexpr int Bc = 8, Dc = 128, Hc = 128, Wc = 128;

// 16B vector load at 8B-aligned addresses: CDNA global loads require only
// dword alignment, so global_load_dwordx4 at float2 granularity is fine.
typedef float float4v __attribute__((ext_vector_type(4)));
typedef float float2v __attribute__((ext_vector_type(2)));

struct GP {
    int   l0a, l0b, l1a, l1b, bp;
    float w0a, w0b, w1a, w1b, wlo, whi;
};

// Per-voxel gather parameters from the reference coordinate (r0,r1,r2).
// Weights are computed against the CLAMPED corner location, per reference.
__device__ __forceinline__ GP mkgp(float r0, float r1, float r2) {
    GP g;
    const int i0 = (int)floorf(r0);
    const int i1 = (int)floorf(r1);
    const int i2 = (int)floorf(r2);

    g.l0a = min(max(i0,     0), Dc - 1);
    g.l0b = min(max(i0 + 1, 0), Dc - 1);
    g.l1a = min(max(i1,     0), Hc - 1);
    g.l1b = min(max(i1 + 1, 0), Hc - 1);

    g.w0a = fmaxf(1.0f - fabsf(r0 - (float)g.l0a), 0.0f);
    g.w0b = fmaxf(1.0f - fabsf(r0 - (float)g.l0b), 0.0f);
    g.w1a = fmaxf(1.0f - fabsf(r1 - (float)g.l1a), 0.0f);
    g.w1b = fmaxf(1.0f - fabsf(r1 - (float)g.l1b), 0.0f);

    // w axis: both corners from one 16B pair load at bp (float2 elems bp,bp+1).
    //   interior       : wlo = w2a, whi = w2b
    //   i2 < 0  (clamp): both corners at elem 0   -> wlo = w2a+w2b, whi = 0
    //   i2 > 126(clamp): both corners at elem 127 -> wlo = 0, whi = w2a+w2b
    g.bp = min(max(i2, 0), Wc - 2);
    const int l2a = min(max(i2,     0), Wc - 1);
    const int l2b = min(max(i2 + 1, 0), Wc - 1);
    const float w2a = fmaxf(1.0f - fabsf(r2 - (float)l2a), 0.0f);
    const float w2b = fmaxf(1.0f - fabsf(r2 - (float)l2b), 0.0f);
    g.wlo = (i2 > 126) ? 0.0f        : (w2a + ((i2 < 0) ? w2b : 0.0f));
    g.whi = (i2 > 126) ? (w2a + w2b) : ((i2 < 0) ? 0.0f : w2b);
    return g;
}

__global__ __launch_bounds__(256) void affine_trilinear_kernel(
    const float* __restrict__ images,      // (B,D,H,W,C) fp32
    const float* __restrict__ mats,        // (B,3,4) fp32
    float* __restrict__ out)               // (B,D,H,W,C) fp32
{
    const int tid    = threadIdx.x;
    const int lane_w = tid & 63;           // 64 consecutive w per wave
    const int lane_h = tid >> 6;           // 4 row-pairs per block

    const int bi = blockIdx.x;
    const int wh = bi & 1;                 // w half
    const int h8 = (bi >> 1) & 15;         // 8-row group
    const int d  = (bi >> 5) & (Dc - 1);
    const int b  = bi >> 12;               // uniform per block -> scalar

    const int w  = wh * 64 + lane_w;
    const int h0 = h8 * 8 + lane_h * 2;    // this thread: rows h0 and h0+1

    const float* m = mats + b * 12;
    const float th00 = m[0] * 0.2f + 1.0f;
    const float th01 = m[1] * 0.2f;
    const float th02 = m[2] * 0.2f;
    const float th10 = m[4] * 0.2f;
    const float th11 = m[5] * 0.2f + 1.0f;
    const float th12 = m[6] * 0.2f;
    const float th20 = m[8] * 0.2f;
    const float th21 = m[9] * 0.2f;
    const float th22 = m[10] * 0.2f + 1.0f;
    const float t   = m[3] * 0.2f;                 // ref uses only m[0,3]
    const float off = 128.0f * (t + 0.5f) - 0.5f;  // dims are all 128

    // grid value: index - dim/2 - 0.5 = index - 64.5
    const float gx = (float)d  - 64.5f;
    const float gy = (float)h0 - 64.5f;
    const float gz = (float)w  - 64.5f;

    const float r0A = gx * th00 + gy * th01 + gz * th02 + off;
    const float r1A = gx * th10 + gy * th11 + gz * th12 + off;
    const float r2A = gx * th20 + gy * th21 + gz * th22 + off;
    // Row h0+1: add theta's y column.
    const float r0B = r0A + th01;
    const float r1B = r1A + th11;
    const float r2B = r2A + th21;

    const GP A = mkgp(r0A, r1A, r2A);
    const GP Bg = mkgp(r0B, r1B, r2B);

    const float2* img = (const float2*)images + (size_t)b * (Dc * Hc * Wc);

    // Issue all 8 independent loads first (max memory-level parallelism).
    float4v vA[4], vB[4];
    #pragma unroll
    for (int s = 0; s < 4; ++s) {
        const int l0A = (s & 2) ? A.l0b : A.l0a;
        const int l1A = (s & 1) ? A.l1b : A.l1a;
        vA[s] = *(const float4v*)(img + ((size_t)l0A * Hc + l1A) * Wc + A.bp);
        const int l0B = (s & 2) ? Bg.l0b : Bg.l0a;
        const int l1B = (s & 1) ? Bg.l1b : Bg.l1a;
        vB[s] = *(const float4v*)(img + ((size_t)l0B * Hc + l1B) * Wc + Bg.bp);
    }

    float a0 = 0.0f, a1 = 0.0f, b0 = 0.0f, b1 = 0.0f;
    #pragma unroll
    for (int s = 0; s < 4; ++s) {
        const float wdhA = ((s & 2) ? A.w0b : A.w0a) * ((s & 1) ? A.w1b : A.w1a);
        a0 = fmaf(vA[s].x * A.wlo + vA[s].z * A.whi, wdhA, a0);
        a1 = fmaf(vA[s].y * A.wlo + vA[s].w * A.whi, wdhA, a1);
        const float wdhB = ((s & 2) ? Bg.w0b : Bg.w0a) * ((s & 1) ? Bg.w1b : Bg.w1a);
        b0 = fmaf(vB[s].x * Bg.wlo + vB[s].z * Bg.whi, wdhB, b0);
        b1 = fmaf(vB[s].y * Bg.wlo + vB[s].w * Bg.whi, wdhB, b1);
    }

    // Non-temporal stores: don't let the 134MB output stream evict image
    // lines from L2.
    float2v* po = (float2v*)out + ((((size_t)b * Dc + d) * Hc + h0) * Wc + w);
    float2v oA = {a0, a1};
    float2v oB = {b0, b1};
    __builtin_nontemporal_store(oA, po);
    __builtin_nontemporal_store(oB, po + Wc);

}

extern "C" void kernel_launch(void* const* d_in, const int* in_sizes, int n_in,
                              void* d_out, int out_size, void* d_ws, size_t ws_size,
                              hipStream_t stream) {
    const float* images = (const float*)d_in[0];
    const float* mats   = (const float*)d_in[1];
    float* out          = (float*)d_out;

    const int threads = 256;
    const int blocks  = Bc * Dc * 16 * 2;  // 32768: (b, d, h/8, w-half)
    affine_trilinear_kernel<<<blocks, threads, 0, stream>>>(images, mats, out);
}